// Round 6
// baseline (351.764 us; speedup 1.0000x reference)
//
#include <hip/hip_runtime.h>

// ---------------------------------------------------------------------------
// EdgeLLMAttentionTRTNative: out = X @ (s*Wo@Wq)^T + kv_cache passthrough.
// Round 6: merge 4 phases -> 2 per K-tile (24 MFMA per barrier-pair, was 12)
// to amortize the ~580-cyc/phase barrier+drain overhead seen in round 5
// (MfmaUtil 39%). Same BM=256 BN=192 BK=64, 8 waves 2Mx4N, 2-buffer LDS
// 112KB, chunk-XOR swizzle, vmcnt(3) ladder. Both GEMMs use this kernel.
// ---------------------------------------------------------------------------

typedef __attribute__((ext_vector_type(8))) __bf16 bf16x8;
typedef __attribute__((ext_vector_type(4))) float f32x4;

__device__ __forceinline__ unsigned short f2bf(float f) {
  union { float f; unsigned u; } v; v.f = f;
  unsigned r = v.u + 0x7fffu + ((v.u >> 16) & 1u);   // round-to-nearest-even
  return (unsigned short)(r >> 16);
}

__global__ void cast_f32_to_bf16(const float4* __restrict__ in,
                                 ushort4* __restrict__ out, int n4) {
  int i = blockIdx.x * blockDim.x + threadIdx.x;
  int stride = gridDim.x * blockDim.x;
  for (; i < n4; i += stride) {
    float4 v = in[i];
    ushort4 o;
    o.x = f2bf(v.x); o.y = f2bf(v.y); o.z = f2bf(v.z); o.w = f2bf(v.w);
    out[i] = o;
  }
}

// out (C x R, bf16) = transpose of in (R x C, fp32)
__global__ void transpose_cast(const float* __restrict__ in,
                               ushort* __restrict__ out, int R, int C) {
  __shared__ float tile[32][33];
  const int tc = blockIdx.x * 32;
  const int tr = blockIdx.y * 32;
  const int lx = threadIdx.x & 31;
  const int ly = threadIdx.x >> 5;
#pragma unroll
  for (int i = 0; i < 32; i += 8)
    tile[ly + i][lx] = in[(size_t)(tr + ly + i) * C + (tc + lx)];
  __syncthreads();
#pragma unroll
  for (int i = 0; i < 32; i += 8)
    out[(size_t)(tc + ly + i) * R + (tr + lx)] = f2bf(tile[lx][ly + i]);
}

typedef const __attribute__((address_space(1))) void* gptr_t;
typedef __attribute__((address_space(3))) void* lptr_t;

__device__ __forceinline__ void gload16(const void* g, void* l) {
  __builtin_amdgcn_global_load_lds((gptr_t)g, (lptr_t)l, 16, 0, 0);
}

#define BAR   do { asm volatile("" ::: "memory"); __builtin_amdgcn_s_barrier(); asm volatile("" ::: "memory"); } while (0)
#define LGKM0 asm volatile("s_waitcnt lgkmcnt(0)" ::: "memory")
#define VM(n) asm volatile("s_waitcnt vmcnt(" #n ")" ::: "memory")

// ---------------------------------------------------------------------------
// GEMM: C = A(MxK) * B(NxK)^T, bf16 in, f32 or scaled-bf16 out.
// BM=256 BN=192 BK=64; 8 waves 2Mx4N, per-wave 128x48, acc[8][3].
// LDS buffer: A[256][64] 32KB + B[192][64] 24KB; x2 = 112KB -> 1 block/CU.
// 2 phases per K-tile, 24 MFMA each:
//   Ph1(T): read aM1 (A mh1, kh0+kh1, 8 b128); stage B(T+2);
//           BAR; LGKM0; MFMA mh0 (aM0 x Bcur); VM(3|0); BAR.
//   Ph2(T): read aM0/Bnext of tile T+1 (14 b128); stage A_LOW+A_HIGH(T+2);
//           BAR; LGKM0; MFMA mh1 (aM1 x Bcur); BAR.
// Lifetime proof: B(bo) frag reads drain in Ph2(T-1) pre-end-BAR -> stage
// B(T+2)@Ph1(T) safe; A(bo) reads drain in Ph1(T)/Ph2(T-1) -> stage A@Ph2(T)
// safe; Ph2 reads touch bon only, stages touch bo only.
// vmcnt(3) after Ph1-MFMA: only B(T+2) may remain in flight => all 7 loads
// of tile T+1 landed; barrier makes it global before Ph2's read-ahead.
// Tail T>=nt-2: no B(T+2) staged -> vmcnt(0). B-frags ping-pong BA/BB
// (loop unrolled x2 to keep static register names).
// ---------------------------------------------------------------------------
template <int OUT_BF16>
__global__ __launch_bounds__(512, 2)
void gemm_k(const ushort* __restrict__ A, const ushort* __restrict__ B,
            void* __restrict__ Cv, int M, int N, int K, float scale) {
  __shared__ __align__(16) char smem[114688];

  const int t    = threadIdx.x;
  const int w    = t >> 6;
  const int lane = t & 63;
  const int wr   = w >> 2;             // 0..1  (M: 128 rows each)
  const int wc   = w & 3;              // 0..3  (N: 48 cols each)
  const int fr   = lane & 15;
  const int g    = lane >> 4;          // 0..3

  // XCD-aware bijective swizzle: nwg % 8 == 0 by construction.
  const int nwg = gridDim.x;
  const int cpx = nwg >> 3;
  const int wg  = (blockIdx.x & 7) * cpx + (blockIdx.x >> 3);
  const int nbx = N / 192;
  const int bx  = wg % nbx, by = wg / nbx;
  const int rowBase = by * 256, colBase = bx * 192;

  // Staging: pass covers 64 rows; wave w rows [w*8, w*8+8); lane l row +l>>3,
  // stored chunk l&7 holds logical chunk (l&7)^(l>>3)  (row&7 == l>>3).
  const int sr   = lane >> 3;                       // 0..7
  const int scol = ((lane & 7) ^ sr) << 3;          // pre-swizzled source col
  const ushort* Ag = A + (size_t)(rowBase + w * 8 + sr) * K + scol;
  const ushort* Bg = B + (size_t)(colBase + w * 8 + sr) * K + scol;
  const int wofs = w * 1024;                        // wave LDS byte offset

#define STAGE_A_LOW(kt)  do { char* d_ = smem + ((kt) & 1) * 57344 + wofs;          \
    const ushort* s_ = Ag + (size_t)(kt) * 64;                                      \
    gload16(s_, d_); gload16(s_ + (size_t)64 * K, d_ + 8192); } while (0)
#define STAGE_A_HIGH(kt) do { char* d_ = smem + ((kt) & 1) * 57344 + 16384 + wofs;  \
    const ushort* s_ = Ag + (size_t)128 * K + (size_t)(kt) * 64;                    \
    gload16(s_, d_); gload16(s_ + (size_t)64 * K, d_ + 8192); } while (0)
#define STAGE_B(kt)      do { char* d_ = smem + ((kt) & 1) * 57344 + 32768 + wofs;  \
    const ushort* s_ = Bg + (size_t)(kt) * 64;                                      \
    gload16(s_, d_); gload16(s_ + (size_t)64 * K, d_ + 8192);                       \
    gload16(s_ + (size_t)128 * K, d_ + 16384); } while (0)

  // Fragment read geometry (byte offsets). Row stride 128B; logical chunk
  // kh*4+g stored at (kh*4+g)^(fr&7) since row&7 == fr&7 for all frag rows.
  const int aBase = (wr * 128 + fr) * 128;
  const int bBase = 32768 + (wc * 48 + fr) * 128;
  const int cs0   = (g ^ (fr & 7)) << 4;            // kh=0
  const int cs1   = ((4 | g) ^ (fr & 7)) << 4;      // kh=1

#define READ_A8(dst, bo, MH) do {                                     \
    const char* p_ = smem + (bo) + aBase + (MH) * 8192;               \
    dst[0] = *(const bf16x8*)(p_ + cs0);                              \
    dst[1] = *(const bf16x8*)(p_ + 2048 + cs0);                       \
    dst[2] = *(const bf16x8*)(p_ + 4096 + cs0);                       \
    dst[3] = *(const bf16x8*)(p_ + 6144 + cs0);                       \
    dst[4] = *(const bf16x8*)(p_ + cs1);                              \
    dst[5] = *(const bf16x8*)(p_ + 2048 + cs1);                       \
    dst[6] = *(const bf16x8*)(p_ + 4096 + cs1);                       \
    dst[7] = *(const bf16x8*)(p_ + 6144 + cs1); } while (0)
#define READ_B6(dst, bo) do {                                         \
    const char* p_ = smem + (bo) + bBase;                             \
    dst[0] = *(const bf16x8*)(p_ + cs0);                              \
    dst[1] = *(const bf16x8*)(p_ + 2048 + cs0);                       \
    dst[2] = *(const bf16x8*)(p_ + 4096 + cs0);                       \
    dst[3] = *(const bf16x8*)(p_ + cs1);                              \
    dst[4] = *(const bf16x8*)(p_ + 2048 + cs1);                       \
    dst[5] = *(const bf16x8*)(p_ + 4096 + cs1); } while (0)
// 24 MFMA: mh half x {kh0: A[0..3]xB[0..2], kh1: A[4..7]xB[3..5]}
#define MFMA24(MH, A8, B6) do {                                       \
    _Pragma("unroll") for (int mi_ = 0; mi_ < 4; ++mi_)               \
    _Pragma("unroll") for (int ni_ = 0; ni_ < 3; ++ni_)               \
      acc[(MH) * 4 + mi_][ni_] = __builtin_amdgcn_mfma_f32_16x16x32_bf16( \
          A8[mi_], B6[ni_], acc[(MH) * 4 + mi_][ni_], 0, 0, 0);       \
    _Pragma("unroll") for (int mi_ = 0; mi_ < 4; ++mi_)               \
    _Pragma("unroll") for (int ni_ = 0; ni_ < 3; ++ni_)               \
      acc[(MH) * 4 + mi_][ni_] = __builtin_amdgcn_mfma_f32_16x16x32_bf16( \
          A8[4 + mi_], B6[3 + ni_], acc[(MH) * 4 + mi_][ni_], 0, 0, 0); } while (0)

  f32x4 acc[8][3];
#pragma unroll
  for (int m = 0; m < 8; ++m)
#pragma unroll
    for (int n = 0; n < 3; ++n)
      acc[m][n] = f32x4{0.f, 0.f, 0.f, 0.f};

  bf16x8 aM0[8], aM1[8], BA[6], BB[6];

  const int nt = K >> 6;               // 48 (even)

  // Prologue: stage tiles 0,1; wait tile 0; pre-read aM0/BA of tile 0;
  // drain those reads + barrier so Ph1(0)'s B(2) stage can't race them.
  STAGE_A_LOW(0); STAGE_B(0); STAGE_A_HIGH(0);
  STAGE_A_LOW(1); STAGE_B(1); STAGE_A_HIGH(1);
  VM(7);
  BAR;
  READ_A8(aM0, 0, 0);
  READ_B6(BA, 0);
  LGKM0;
  BAR;

#define TILE_BODY(T, BC, BN_) do {                                            \
    const int bo_  = ((T) & 1) * 57344;                                       \
    const int bon_ = 57344 - bo_;                                             \
    const bool stg_ = (T) + 2 < nt;                                           \
    /* Ph1 */                                                                 \
    READ_A8(aM1, bo_, 1);                                                     \
    if (stg_) STAGE_B((T) + 2);                                               \
    BAR; LGKM0;                                                               \
    __builtin_amdgcn_s_setprio(1); MFMA24(0, aM0, BC); __builtin_amdgcn_s_setprio(0); \
    if ((T) < nt - 2) { VM(3); } else { VM(0); }                              \
    BAR;                                                                      \
    /* Ph2 */                                                                 \
    if ((T) + 1 < nt) { READ_A8(aM0, bon_, 0); READ_B6(BN_, bon_); }          \
    if (stg_) { STAGE_A_LOW((T) + 2); STAGE_A_HIGH((T) + 2); }                \
    BAR; LGKM0;                                                               \
    __builtin_amdgcn_s_setprio(1); MFMA24(1, aM1, BC); __builtin_amdgcn_s_setprio(0); \
    BAR;                                                                      \
  } while (0)

  for (int TT = 0; TT < nt; TT += 2) {
    TILE_BODY(TT, BA, BB);
    TILE_BODY(TT + 1, BB, BA);
  }

#undef TILE_BODY
#undef STAGE_A_LOW
#undef STAGE_A_HIGH
#undef STAGE_B
#undef READ_A8
#undef READ_B6
#undef MFMA24

  // C/D layout: col = lane&15, row = (lane>>4)*4 + i
  const int orow = rowBase + wr * 128 + (g << 2);
  const int ocol = colBase + wc * 48 + fr;
#pragma unroll
  for (int mi = 0; mi < 8; ++mi)
#pragma unroll
    for (int ni = 0; ni < 3; ++ni)
#pragma unroll
      for (int i = 0; i < 4; ++i) {
        const size_t idx = (size_t)(orow + mi * 16 + i) * N + (ocol + ni * 16);
        float v = acc[mi][ni][i] * scale;
        if (OUT_BF16) ((ushort*)Cv)[idx] = f2bf(v);
        else          ((float*)Cv)[idx]  = v;
      }
}

extern "C" void kernel_launch(void* const* d_in, const int* in_sizes, int n_in,
                              void* d_out, int out_size, void* d_ws, size_t ws_size,
                              hipStream_t stream) {
  const float* hs = (const float*)d_in[0];   // (4,2048,3072)
  const float* kv = (const float*)d_in[4];   // (4,2,8,4096,128)
  const float* Wq = (const float*)d_in[5];   // (3072,3072) (d,h)
  const float* Wo = (const float*)d_in[8];   // (3072,3072) (o,d)

  const int M = 8192, H = 3072;
  const int OUT_ELEMS = M * H;

  float* out = (float*)d_out;

  ushort* Xb   = (ushort*)d_ws;
  ushort* Wob  = Xb + (size_t)M * H;
  ushort* WqTb = Wob + (size_t)H * H;
  // Fused weight W = s*Wo@Wq (bf16) in the kv-tail of d_out; overwritten by
  // the kv_cache copy afterwards (stream-ordered).
  ushort* Wb   = (ushort*)(out + OUT_ELEMS);

  cast_f32_to_bf16<<<2048, 256, 0, stream>>>((const float4*)hs, (ushort4*)Xb, (M * H) / 4);
  cast_f32_to_bf16<<<1024, 256, 0, stream>>>((const float4*)Wo, (ushort4*)Wob, (H * H) / 4);
  transpose_cast<<<dim3(H / 32, H / 32), 256, 0, stream>>>(Wq, WqTb, H, H);

  const float qk_scale = 0.08838834764831845f;  // 128^-0.5
  // W[o,h] = s * sum_d Wo[o,d] * Wq[d,h]   (grid 12*16 = 192, %8==0)
  gemm_k<1><<<(H / 256) * (H / 192), 512, 0, stream>>>(Wob, WqTb, (void*)Wb, H, H, H, qk_scale);
  // out[m,o] = sum_h X[m,h] * W[o,h]       (grid 32*16 = 512, %8==0)
  gemm_k<0><<<(M / 256) * (H / 192), 512, 0, stream>>>(Xb, Wb, (void*)out, M, H, H, 1.0f);

  hipMemcpyAsync(out + OUT_ELEMS, kv, (size_t)in_sizes[4] * sizeof(float),
                 hipMemcpyDeviceToDevice, stream);
}